// Round 2
// baseline (168.659 us; speedup 1.0000x reference)
//
#include <hip/hip_runtime.h>

#define NB 4
#define NC 64
#define NH 256
#define NW 256
#define TH 32          // output rows per block
#define LR 38          // TH + 6 halo rows
#define LSTR 264       // LDS row stride in floats (global cols -4 .. 259)
#define NCHUNK 66      // float4 chunks per LDS row

__global__ __launch_bounds__(256, 4)
void adaptive_gauss7(const float* __restrict__ x,
                     const float* __restrict__ persp,
                     const float* __restrict__ alpha_p,
                     const float* __restrict__ beta_p,
                     const float* __restrict__ gamma_p,
                     float* __restrict__ out)
{
    __shared__ float xs[LR * LSTR];   // 40128 B -> 4 blocks/CU (LDS-limited)

    const int tid  = threadIdx.x;
    const int lane = tid & 63;        // 64 lanes -> 64 column groups (4 cols each)
    const int trow = tid >> 6;        // 0..3 -> 8-row strip each
    const int c    = blockIdx.x;      // channel fastest: concurrent blocks share persp in L2
    const int h0   = blockIdx.y * TH;
    const int b    = blockIdx.z;
    const int colbase = lane * 4;     // output col base (global)
    const int rbase   = trow * 8;     // first output row (relative to h0)

    const float alpha = alpha_p[0];
    const float beta  = beta_p[0];
    const float gamma = gamma_p[0];

    // ---- issue perspective loads early (independent of staging) ----
    float4 pv4[8];
    {
        const float* pp = persp + (size_t)b * NH * NW;
        #pragma unroll
        for (int r = 0; r < 8; ++r) {
            const int h = h0 + rbase + r;
            pv4[r] = *(const float4*)(pp + (size_t)h * NW + colbase);
        }
    }

    // ---- stage x tile: rows h0-3 .. h0+34, cols -4 .. 259 (zero-padded OOB) ----
    const float* xp = x + (size_t)(b * NC + c) * NH * NW;
    for (int idx = tid; idx < LR * NCHUNK; idx += 256) {
        const int r  = idx / NCHUNK;
        const int c4 = idx - r * NCHUNK;
        const int gr = h0 - 3 + r;
        const int gc = c4 * 4 - 4;
        float4 v = make_float4(0.f, 0.f, 0.f, 0.f);
        if ((unsigned)gr < NH && (unsigned)gc < NW)
            v = *(const float4*)(xp + (size_t)gr * NW + gc);
        *(float4*)(&xs[r * LSTR + c4 * 4]) = v;
    }

    // ---- per-pixel g = exp(-1/(2*sigma^2)) while staging drains ----
    float gw[8][4];
    #pragma unroll
    for (int r = 0; r < 8; ++r) {
        const float pv[4] = {pv4[r].x, pv4[r].y, pv4[r].z, pv4[r].w};
        #pragma unroll
        for (int k = 0; k < 4; ++k) {
            const float z  = fmaf(beta, pv[k], gamma);
            const float sg = __builtin_amdgcn_rcpf(1.0f + __expf(-z));
            const float sigma = fmaxf(alpha * sg, 1e-4f);
            const float t  = 0.5f * __builtin_amdgcn_rcpf(sigma * sigma);
            gw[r][k] = __expf(-t);   // g; weights are g^(d^2)
        }
    }

    __syncthreads();

    // ---- sliding 7-row window in registers, 12 floats wide ----
    float win[7][12];
    #pragma unroll
    for (int i = 0; i < 7; ++i) {
        const float* src = &xs[(rbase + i) * LSTR + colbase];
        const float4 a0 = *(const float4*)(src);
        const float4 a1 = *(const float4*)(src + 4);
        const float4 a2 = *(const float4*)(src + 8);
        win[i][0] = a0.x; win[i][1] = a0.y; win[i][2]  = a0.z; win[i][3]  = a0.w;
        win[i][4] = a1.x; win[i][5] = a1.y; win[i][6]  = a1.z; win[i][7]  = a1.w;
        win[i][8] = a2.x; win[i][9] = a2.y; win[i][10] = a2.z; win[i][11] = a2.w;
    }

    float* outp = out + (size_t)(b * NC + c) * NH * NW
                      + (size_t)(h0 + rbase) * NW + colbase;

    #pragma unroll
    for (int orow = 0; orow < 8; ++orow) {
        if (orow > 0) {   // advance window: load LDS row rbase+orow+6
            const int wi = (orow + 6) % 7;
            const float* src = &xs[(rbase + orow + 6) * LSTR + colbase];
            const float4 a0 = *(const float4*)(src);
            const float4 a1 = *(const float4*)(src + 4);
            const float4 a2 = *(const float4*)(src + 8);
            win[wi][0] = a0.x; win[wi][1] = a0.y; win[wi][2]  = a0.z; win[wi][3]  = a0.w;
            win[wi][4] = a1.x; win[wi][5] = a1.y; win[wi][6]  = a1.z; win[wi][7]  = a1.w;
            win[wi][8] = a2.x; win[wi][9] = a2.y; win[wi][10] = a2.z; win[wi][11] = a2.w;
        }
        float res[4];
        #pragma unroll
        for (int k = 0; k < 4; ++k) {
            const float g  = gw[orow][k];
            const float g2 = g * g;
            const float p4 = g2 * g2;          // g^4
            const float p9 = p4 * p4 * g;      // g^9
            const float S  = fmaf(2.0f, (g + p4) + p9, 1.0f);
            const float inv  = __builtin_amdgcn_rcpf(S);
            const float inv2 = inv * inv;      // 1/S^2
            float rs[7];
            #pragma unroll
            for (int j = 0; j < 7; ++j) {
                const int wr = (orow + j) % 7;   // window row holding LDS row rbase+orow+j
                rs[j] = fmaf(p9, win[wr][k+1] + win[wr][k+7],
                        fmaf(p4, win[wr][k+2] + win[wr][k+6],
                        fmaf(g,  win[wr][k+3] + win[wr][k+5],
                                 win[wr][k+4])));
            }
            const float acc = fmaf(p9, rs[0] + rs[6],
                              fmaf(p4, rs[1] + rs[5],
                              fmaf(g,  rs[2] + rs[4],
                                       rs[3])));
            res[k] = acc * inv2;
        }
        *(float4*)(outp + (size_t)orow * NW) =
            make_float4(res[0], res[1], res[2], res[3]);
    }
}

extern "C" void kernel_launch(void* const* d_in, const int* in_sizes, int n_in,
                              void* d_out, int out_size, void* d_ws, size_t ws_size,
                              hipStream_t stream) {
    const float* x     = (const float*)d_in[0];
    const float* persp = (const float*)d_in[1];
    const float* alpha = (const float*)d_in[2];
    const float* beta  = (const float*)d_in[3];
    const float* gamma = (const float*)d_in[4];
    float* outp        = (float*)d_out;
    // kernel_size (d_in[5]) is fixed at 7 per the reference setup
    dim3 grid(NC, NH / TH, NB);   // 64 x 8 x 4 = 2048 blocks
    adaptive_gauss7<<<grid, dim3(256), 0, stream>>>(x, persp, alpha, beta, gamma, outp);
}

// Round 3
// 157.398 us; speedup vs baseline: 1.0715x; 1.0715x over previous
//
#include <hip/hip_runtime.h>

#define NB 4
#define NC 64
#define NH 256
#define NW 256
#define TH 32          // output rows per block
#define LR 38          // TH + 6 halo rows
#define LSTR 264       // LDS row stride in floats (global cols -4 .. 259)
#define NCHUNK 66      // float4 chunks per LDS row

// launch_bounds(256,2): empirically VGPR=128, no scratch spill (round 1).
// (256,4) forced VGPR=64 -> 70 MB of spill traffic (round 2 post-mortem).
__global__ __launch_bounds__(256, 2)
void adaptive_gauss7(const float* __restrict__ x,
                     const float* __restrict__ persp,
                     const float* __restrict__ alpha_p,
                     const float* __restrict__ beta_p,
                     const float* __restrict__ gamma_p,
                     float* __restrict__ out)
{
    __shared__ float xs[LR * LSTR];   // 40128 B -> 4 blocks/CU (LDS-limited)

    const int tid  = threadIdx.x;
    const int lane = tid & 63;        // 64 lanes -> 64 column groups (4 cols each)
    const int trow = tid >> 6;        // 0..3 -> 8-row strip each
    const int c    = blockIdx.x;      // channel fastest: concurrent blocks share persp in L2
    const int h0   = blockIdx.y * TH;
    const int b    = blockIdx.z;
    const int colbase = lane * 4;     // output col base (global)
    const int rbase   = trow * 8;     // first output row (relative to h0)

    const float alpha = alpha_p[0];
    const float beta  = beta_p[0];
    const float gamma = gamma_p[0];

    // ---- issue perspective loads early (independent of staging) ----
    float4 pv4[8];
    {
        const float* pp = persp + (size_t)b * NH * NW;
        #pragma unroll
        for (int r = 0; r < 8; ++r) {
            const int h = h0 + rbase + r;
            pv4[r] = *(const float4*)(pp + (size_t)h * NW + colbase);
        }
    }

    // ---- stage x tile: rows h0-3 .. h0+34, cols -4 .. 259 (zero-padded OOB) ----
    const float* xp = x + (size_t)(b * NC + c) * NH * NW;
    for (int idx = tid; idx < LR * NCHUNK; idx += 256) {
        const int r  = idx / NCHUNK;
        const int c4 = idx - r * NCHUNK;
        const int gr = h0 - 3 + r;
        const int gc = c4 * 4 - 4;
        float4 v = make_float4(0.f, 0.f, 0.f, 0.f);
        if ((unsigned)gr < NH && (unsigned)gc < NW)
            v = *(const float4*)(xp + (size_t)gr * NW + gc);
        *(float4*)(&xs[r * LSTR + c4 * 4]) = v;
    }

    // ---- per-pixel g = exp(-1/(2*sigma^2)) while staging drains ----
    float gw[8][4];
    #pragma unroll
    for (int r = 0; r < 8; ++r) {
        const float pv[4] = {pv4[r].x, pv4[r].y, pv4[r].z, pv4[r].w};
        #pragma unroll
        for (int k = 0; k < 4; ++k) {
            const float z  = fmaf(beta, pv[k], gamma);
            const float sg = __builtin_amdgcn_rcpf(1.0f + __expf(-z));
            const float sigma = fmaxf(alpha * sg, 1e-4f);
            const float t  = 0.5f * __builtin_amdgcn_rcpf(sigma * sigma);
            gw[r][k] = __expf(-t);   // g; weights are g^(d^2)
        }
    }

    __syncthreads();

    // ---- sliding 7-row window in registers, 12 floats wide ----
    float win[7][12];
    #pragma unroll
    for (int i = 0; i < 7; ++i) {
        const float* src = &xs[(rbase + i) * LSTR + colbase];
        const float4 a0 = *(const float4*)(src);
        const float4 a1 = *(const float4*)(src + 4);
        const float4 a2 = *(const float4*)(src + 8);
        win[i][0] = a0.x; win[i][1] = a0.y; win[i][2]  = a0.z; win[i][3]  = a0.w;
        win[i][4] = a1.x; win[i][5] = a1.y; win[i][6]  = a1.z; win[i][7]  = a1.w;
        win[i][8] = a2.x; win[i][9] = a2.y; win[i][10] = a2.z; win[i][11] = a2.w;
    }

    float* outp = out + (size_t)(b * NC + c) * NH * NW
                      + (size_t)(h0 + rbase) * NW + colbase;

    #pragma unroll
    for (int orow = 0; orow < 8; ++orow) {
        if (orow > 0) {   // advance window: load LDS row rbase+orow+6
            const int wi = (orow + 6) % 7;
            const float* src = &xs[(rbase + orow + 6) * LSTR + colbase];
            const float4 a0 = *(const float4*)(src);
            const float4 a1 = *(const float4*)(src + 4);
            const float4 a2 = *(const float4*)(src + 8);
            win[wi][0] = a0.x; win[wi][1] = a0.y; win[wi][2]  = a0.z; win[wi][3]  = a0.w;
            win[wi][4] = a1.x; win[wi][5] = a1.y; win[wi][6]  = a1.z; win[wi][7]  = a1.w;
            win[wi][8] = a2.x; win[wi][9] = a2.y; win[wi][10] = a2.z; win[wi][11] = a2.w;
        }
        float res[4];
        #pragma unroll
        for (int k = 0; k < 4; ++k) {
            const float g  = gw[orow][k];
            const float g2 = g * g;
            const float p4 = g2 * g2;          // g^4
            const float p9 = p4 * p4 * g;      // g^9
            const float S  = fmaf(2.0f, (g + p4) + p9, 1.0f);
            const float inv  = __builtin_amdgcn_rcpf(S);
            const float inv2 = inv * inv;      // 1/S^2
            float rs[7];
            #pragma unroll
            for (int j = 0; j < 7; ++j) {
                const int wr = (orow + j) % 7;   // window row holding LDS row rbase+orow+j
                rs[j] = fmaf(p9, win[wr][k+1] + win[wr][k+7],
                        fmaf(p4, win[wr][k+2] + win[wr][k+6],
                        fmaf(g,  win[wr][k+3] + win[wr][k+5],
                                 win[wr][k+4])));
            }
            const float acc = fmaf(p9, rs[0] + rs[6],
                              fmaf(p4, rs[1] + rs[5],
                              fmaf(g,  rs[2] + rs[4],
                                       rs[3])));
            res[k] = acc * inv2;
        }
        *(float4*)(outp + (size_t)orow * NW) =
            make_float4(res[0], res[1], res[2], res[3]);
    }
}

extern "C" void kernel_launch(void* const* d_in, const int* in_sizes, int n_in,
                              void* d_out, int out_size, void* d_ws, size_t ws_size,
                              hipStream_t stream) {
    const float* x     = (const float*)d_in[0];
    const float* persp = (const float*)d_in[1];
    const float* alpha = (const float*)d_in[2];
    const float* beta  = (const float*)d_in[3];
    const float* gamma = (const float*)d_in[4];
    float* outp        = (float*)d_out;
    // kernel_size (d_in[5]) is fixed at 7 per the reference setup
    dim3 grid(NC, NH / TH, NB);   // 64 x 8 x 4 = 2048 blocks
    adaptive_gauss7<<<grid, dim3(256), 0, stream>>>(x, persp, alpha, beta, gamma, outp);
}

// Round 4
// 152.547 us; speedup vs baseline: 1.1056x; 1.0318x over previous
//
#include <hip/hip_runtime.h>

#define NB 4
#define NC 64
#define NH 256
#define NW 256
#define TH 32                   // output rows per block
#define LR 38                   // TH + 6 halo rows
#define LSTR 264                // LDS row stride in floats (= 66 chunks * 4)
#define NCHUNK 66               // 16B chunks per LDS row
#define NCHUNKS_TOT (LR * NCHUNK)      // 2508 chunks
#define BUF_BYTES (NCHUNKS_TOT * 16)   // 40128 B per buffer
#define CH_PER 4

// zero-initialized device global: OOB staging taps read 16B of zeros from here.
// Never written; harness only poisons d_out/d_ws.
__device__ float g_zero[16] __attribute__((aligned(64)));

static __device__ __forceinline__ void async16(const void* g, void* l) {
    // global -> LDS direct DMA, 16B/lane. LDS dest = wave-uniform base + lane*16.
    __builtin_amdgcn_global_load_lds(
        (const __attribute__((address_space(1))) void*)g,
        (__attribute__((address_space(3))) void*)l, 16, 0, 0);
}

// (256,2): VGPR cap 256 -> no spill (round-2 lesson: (256,4) forced 64 VGPR -> 70MB spill)
__global__ __launch_bounds__(256, 2)
void adaptive_gauss7(const float* __restrict__ x,
                     const float* __restrict__ persp,
                     const float* __restrict__ alpha_p,
                     const float* __restrict__ beta_p,
                     const float* __restrict__ gamma_p,
                     float* __restrict__ out)
{
    __shared__ char xs_raw[2 * BUF_BYTES];   // 80256 B -> 2 blocks/CU

    const int tid  = threadIdx.x;
    const int lane = tid & 63;
    const int wv   = tid >> 6;          // 4 waves
    const int c0   = blockIdx.x * CH_PER;
    const int h0   = blockIdx.y * TH;
    const int b    = blockIdx.z;
    const int colbase = lane * 4;       // output col base
    const int rbase   = wv * 8;         // first output row in tile

    const float alpha = alpha_p[0];
    const float beta  = beta_p[0];
    const float gamma = gamma_p[0];

    // ---- perspective loads first (oldest in vmcnt queue) ----
    float4 pv4[8];
    {
        const float* pp = persp + (size_t)b * NH * NW;
        #pragma unroll
        for (int r = 0; r < 8; ++r)
            pv4[r] = *(const float4*)(pp + (size_t)(h0 + rbase + r) * NW + colbase);
    }

    // ---- precompute per-thread staging offsets (reused for all 4 channels) ----
    // chunk q -> LDS byte off q*16; row r=q/66, byte-in-row cb=(q%66)*16-16
    int offs[10];
    #pragma unroll
    for (int it = 0; it < 10; ++it) {
        const int q  = it * 256 + tid;
        const int r  = q / NCHUNK;
        const int cb = (q - r * NCHUNK) * 16 - 16;
        const int gr = h0 - 3 + r;
        const bool valid = ((unsigned)gr < NH) && ((unsigned)cb < NW * 4);
        offs[it] = valid ? (gr * (NW * 4) + cb) : -1;
    }

    const char* xbase = (const char*)x + (size_t)(b * NC + c0) * NH * NW * 4;

    // ---- async stage: one channel tile -> one LDS buffer ----
    auto stage = [&](int bufsel, int ci) {
        const char* xc = xbase + (size_t)ci * NH * NW * 4;
        char* lb = xs_raw + bufsel * BUF_BYTES + wv * 1024;  // wave-uniform base
        #pragma unroll
        for (int it = 0; it < 10; ++it) {
            if (it < 9 || (it * 256 + tid) < NCHUNKS_TOT) {
                const char* g = (offs[it] >= 0) ? (xc + offs[it]) : (const char*)g_zero;
                async16(g, lb + it * 4096);
            }
        }
    };

    stage(0, 0);   // channel c0 -> buffer 0 (async; overlaps gw compute below)

    // ---- per-pixel g = exp(-1/(2*sigma^2)), once per block (all 4 channels) ----
    float gw[8][4];
    #pragma unroll
    for (int r = 0; r < 8; ++r) {
        const float pv[4] = {pv4[r].x, pv4[r].y, pv4[r].z, pv4[r].w};
        #pragma unroll
        for (int k = 0; k < 4; ++k) {
            const float z  = fmaf(beta, pv[k], gamma);
            const float sg = __builtin_amdgcn_rcpf(1.0f + __expf(-z));
            const float sigma = fmaxf(alpha * sg, 1e-4f);
            const float t  = 0.5f * __builtin_amdgcn_rcpf(sigma * sigma);
            gw[r][k] = __expf(-t);   // g; weights are g^(d^2)
        }
    }

    __syncthreads();   // drains vmcnt -> buffer 0 ready

    for (int ci = 0; ci < CH_PER; ++ci) {
        if (ci + 1 < CH_PER)
            stage((ci + 1) & 1, ci + 1);   // async prefetch next channel; NOT waited here

        const float* xs = (const float*)(xs_raw + (ci & 1) * BUF_BYTES);

        // sliding 7-row window in registers, 12 floats wide
        float win[7][12];
        #pragma unroll
        for (int i = 0; i < 7; ++i) {
            const float* src = &xs[(rbase + i) * LSTR + colbase];
            const float4 a0 = *(const float4*)(src);
            const float4 a1 = *(const float4*)(src + 4);
            const float4 a2 = *(const float4*)(src + 8);
            win[i][0] = a0.x; win[i][1] = a0.y; win[i][2]  = a0.z; win[i][3]  = a0.w;
            win[i][4] = a1.x; win[i][5] = a1.y; win[i][6]  = a1.z; win[i][7]  = a1.w;
            win[i][8] = a2.x; win[i][9] = a2.y; win[i][10] = a2.z; win[i][11] = a2.w;
        }

        float* outp = out + (size_t)(b * NC + c0 + ci) * NH * NW
                          + (size_t)(h0 + rbase) * NW + colbase;

        #pragma unroll
        for (int orow = 0; orow < 8; ++orow) {
            if (orow > 0) {   // advance window
                const int wi = (orow + 6) % 7;
                const float* src = &xs[(rbase + orow + 6) * LSTR + colbase];
                const float4 a0 = *(const float4*)(src);
                const float4 a1 = *(const float4*)(src + 4);
                const float4 a2 = *(const float4*)(src + 8);
                win[wi][0] = a0.x; win[wi][1] = a0.y; win[wi][2]  = a0.z; win[wi][3]  = a0.w;
                win[wi][4] = a1.x; win[wi][5] = a1.y; win[wi][6]  = a1.z; win[wi][7]  = a1.w;
                win[wi][8] = a2.x; win[wi][9] = a2.y; win[wi][10] = a2.z; win[wi][11] = a2.w;
            }
            float res[4];
            #pragma unroll
            for (int k = 0; k < 4; ++k) {
                const float g  = gw[orow][k];
                const float g2 = g * g;
                const float p4 = g2 * g2;          // g^4
                const float p9 = p4 * p4 * g;      // g^9
                const float S  = fmaf(2.0f, (g + p4) + p9, 1.0f);
                const float inv  = __builtin_amdgcn_rcpf(S);
                const float inv2 = inv * inv;      // 1/S^2
                float rs[7];
                #pragma unroll
                for (int j = 0; j < 7; ++j) {
                    const int wr = (orow + j) % 7;
                    rs[j] = fmaf(p9, win[wr][k+1] + win[wr][k+7],
                            fmaf(p4, win[wr][k+2] + win[wr][k+6],
                            fmaf(g,  win[wr][k+3] + win[wr][k+5],
                                     win[wr][k+4])));
                }
                const float acc = fmaf(p9, rs[0] + rs[6],
                                  fmaf(p4, rs[1] + rs[5],
                                  fmaf(g,  rs[2] + rs[4],
                                           rs[3])));
                res[k] = acc * inv2;
            }
            *(float4*)(outp + (size_t)orow * NW) =
                make_float4(res[0], res[1], res[2], res[3]);
        }

        __syncthreads();   // drains prefetch (had whole compute to land) + guards buffer reuse
    }
}

extern "C" void kernel_launch(void* const* d_in, const int* in_sizes, int n_in,
                              void* d_out, int out_size, void* d_ws, size_t ws_size,
                              hipStream_t stream) {
    const float* x     = (const float*)d_in[0];
    const float* persp = (const float*)d_in[1];
    const float* alpha = (const float*)d_in[2];
    const float* beta  = (const float*)d_in[3];
    const float* gamma = (const float*)d_in[4];
    float* outp        = (float*)d_out;
    // kernel_size (d_in[5]) fixed at 7 per the reference setup
    dim3 grid(NC / CH_PER, NH / TH, NB);   // 16 x 8 x 4 = 512 blocks = 2/CU
    adaptive_gauss7<<<grid, dim3(256), 0, stream>>>(x, persp, alpha, beta, gamma, outp);
}